// Round 5
// baseline (119.611 us; speedup 1.0000x reference)
//
#include <hip/hip_runtime.h>
#include <hip/hip_bf16.h>
#include <stdint.h>

// cheb_conv_with_Att_static: out[b,t,v,c] = relu( sum_{k,f} theta[k,f,c] *
//     sum_u cheb[k,u,v]*Att[b,u,v]*x[b,t,u,f] )
// B=8 T=12 V=2048 F=16 K=3 C=64
#define B_  8
#define T_  12
#define V_  2048
#define F_  16
#define K_  3
#define C_  64
#define N_  192   // T*F

typedef _Float16 f16;
typedef _Float16 half4v __attribute__((ext_vector_type(4)));
typedef _Float16 half8v __attribute__((ext_vector_type(8)));
typedef float    f32x4  __attribute__((ext_vector_type(4)));
typedef float    f32x16 __attribute__((ext_vector_type(16)));
typedef unsigned int u32;

// ---------------------------------------------------------------------------
// Kernel 1a: XT[b][n=t*16+f][u] = (f16) x[b][t][u][f]   (u becomes contiguous)
// ---------------------------------------------------------------------------
__global__ __launch_bounds__(256) void prep_xt(const float* __restrict__ x,
                                               f16* __restrict__ XT) {
  int bid = blockIdx.x;
  int bt = bid >> 2, uc = bid & 3;
  int b = bt / T_, t = bt % T_;
  __shared__ float tile[64][17];
  int r  = threadIdx.x >> 2, fq = threadIdx.x & 3;   // load mapping
  int f  = threadIdx.x >> 4, uq = threadIdx.x & 15;  // store mapping
  for (int u0 = uc * 512; u0 < uc * 512 + 512; u0 += 64) {
    f32x4 v = *(const f32x4*)(x + ((size_t)(b * T_ + t) * V_ + u0 + r) * F_ + fq * 4);
    tile[r][fq * 4 + 0] = v[0];
    tile[r][fq * 4 + 1] = v[1];
    tile[r][fq * 4 + 2] = v[2];
    tile[r][fq * 4 + 3] = v[3];
    __syncthreads();
    half4v h;
    h[0] = (f16)tile[uq * 4 + 0][f];
    h[1] = (f16)tile[uq * 4 + 1][f];
    h[2] = (f16)tile[uq * 4 + 2][f];
    h[3] = (f16)tile[uq * 4 + 3][f];
    *(half4v*)(XT + (size_t)(b * N_ + t * F_ + f) * V_ + u0 + uq * 4) = h;
    __syncthreads();
  }
}

// ---------------------------------------------------------------------------
// Kernel 1b: cheb16 = (f16) cheb   (same [k][u][v] layout)
// ---------------------------------------------------------------------------
__global__ __launch_bounds__(256) void prep_cheb(const float* __restrict__ c,
                                                 f16* __restrict__ c16) {
  size_t i = ((size_t)blockIdx.x * 256 + threadIdx.x) * 4;
  f32x4 v = *(const f32x4*)(c + i);
  half4v h;
  h[0] = (f16)v[0]; h[1] = (f16)v[1]; h[2] = (f16)v[2]; h[3] = (f16)v[3];
  *(half4v*)(c16 + i) = h;
}

// ---------------------------------------------------------------------------
// Kernel 2 (k-fused, u-split): per (b,vt,uh): for all 3 k,
//   rhs[b][t][v][uh*48+k*16+f] = sum_{u in half} (cheb[k,u,v]*Att[b,u,v]) * XT[b,n,u]
// BM=64 BN=192 BK=64, 4 waves (2x2), wave tile 32x96, 32x32x16 f16 MFMA.
// Round-5: (a) total regs under the 256 cliff -> 2 waves/SIMD, 2 blocks/CU:
//   the pk[3][4] staging array is gone; products are computed inside writeA
//   AFTER barrier-1 (att/cheb loads had the whole compute phase in flight).
// (b) A swizzle key reverted to (vrow&7)<<4: A ds_read_b128 conflict-free
//   (round-3/4 key (vrow>>2&7) made the 12 A-reads 8-way conflicted, right on
//   the post-barrier MFMA critical path). Write-side b64 conflicts accepted.
// per step: issueA(t+1)->regs; glds B(t+1)->Bb[alt];
//           COMPUTE(t); barrier (vmcnt drain, overlapped);
//           product+writeA(t+1); barrier (lgkm only).
// LDS 72KB (A 24 + B 2x24): 2 blocks/CU.  XCD: b = bid&7 (XT[b] per-XCD L2).
// ---------------------------------------------------------------------------
#define COMPUTE_KS(ks, BPTR)                                                    \
  {                                                                             \
    const int ku2 = (ks) * 32 + (lane >> 5) * 16;                               \
    half8v bfr0 = *(const half8v*)((BPTR) + nrowA[0] * 128 + (ku2 ^ bkeyA[0])); \
    half8v bfr1 = *(const half8v*)((BPTR) + nrowA[1] * 128 + (ku2 ^ bkeyA[1])); \
    half8v bfr2 = *(const half8v*)((BPTR) + nrowA[2] * 128 + (ku2 ^ bkeyA[2])); \
    __builtin_amdgcn_s_setprio(1);                                              \
    _Pragma("unroll")                                                           \
    for (int k = 0; k < 3; ++k) {                                               \
      half8v a = *(const half8v*)(Ab + k * 8192 + vrow * 128 + (ku2 ^ akey));   \
      acc[k][0] = __builtin_amdgcn_mfma_f32_32x32x16_f16(a, bfr0, acc[k][0], 0, 0, 0); \
      acc[k][1] = __builtin_amdgcn_mfma_f32_32x32x16_f16(a, bfr1, acc[k][1], 0, 0, 0); \
      acc[k][2] = __builtin_amdgcn_mfma_f32_32x32x16_f16(a, bfr2, acc[k][2], 0, 0, 0); \
    }                                                                           \
    __builtin_amdgcn_s_setprio(0);                                              \
  }

template<int UH, bool F16C>
__global__ __launch_bounds__(256, 2) void gemm_fused(const float* __restrict__ Att,
                                                     const void* __restrict__ chebp,
                                                     const f16* __restrict__ XT,
                                                     f16* __restrict__ rhs) {
  constexpr int NSTEP = (V_ / UH) / 64;
  const int bid = blockIdx.x;
  const int b  = bid & 7;             // XCD co-location on XT[b]
  const int r2 = bid >> 3;            // 0 .. 32*UH-1
  const int vt = r2 / UH, uh = r2 % UH;
  const int vbase = vt * 64;
  const size_t ubase = (size_t)uh * (V_ / UH);

  __shared__ char smem[73728];        // A 24KB | B0 24KB | B1 24KB
  char* Ab = smem;
  char* Bbuf0 = smem + 24576;
  char* Bbuf1 = smem + 49152;

  const int tid = threadIdx.x;
  const int wave = tid >> 6, lane = tid & 63;
  const int wm = wave >> 1, wn = wave & 1;
  const int vsub = (tid & 15) * 4, usub = (tid >> 4) * 4;

  const float* attb   = Att + (size_t)b * V_ * V_ + vbase + vsub + (size_t)usub * V_;
  const f16*   cb16   = (const f16*)chebp + vbase + vsub + (size_t)usub * V_;
  const float* cbf    = (const float*)chebp + vbase + vsub + (size_t)usub * V_;
  const f16*   xtb    = XT + (size_t)b * N_ * V_;

  f32x16 acc[3][3];
#pragma unroll
  for (int k = 0; k < 3; ++k)
#pragma unroll
    for (int nf = 0; nf < 3; ++nf) acc[k][nf] = 0;

  const int vrow = wm * 32 + (lane & 31);
  const int akey = ((vrow & 7)) << 4;          // conflict-free b128 reads
  int nrowA[3], bkeyA[3];
#pragma unroll
  for (int nf = 0; nf < 3; ++nf) {
    nrowA[nf] = wn * 96 + nf * 32 + (lane & 31);
    bkeyA[nf] = (nrowA[nf] & 7) << 4;
  }
  const int gl_c = (lane & 7) ^ (lane >> 3);   // pre-swizzled glds src chunk

  f32x4  pa[4];
  half4v cv16[3][4];
  f32x4  cvf[3][4];

  auto stageB = [&](size_t u, char* Bb) {
#pragma unroll
    for (int e = 0; e < 6; ++e) {
      int slot = wave * 6 + e;
      int n = slot * 8 + (lane >> 3);
      const f16* src = xtb + (size_t)n * V_ + u + gl_c * 8;
      __builtin_amdgcn_global_load_lds((const __attribute__((address_space(1))) u32*)src,
                                       (__attribute__((address_space(3))) u32*)(Bb + slot * 1024),
                                       16, 0, 0);
    }
  };
  auto issueA = [&](size_t u) {
#pragma unroll
    for (int i = 0; i < 4; ++i) pa[i] = *(const f32x4*)(attb + (u + i) * V_);
    if constexpr (F16C) {
#pragma unroll
      for (int k = 0; k < 3; ++k)
#pragma unroll
        for (int i = 0; i < 4; ++i)
          cv16[k][i] = *(const half4v*)(cb16 + (size_t)k * V_ * V_ + (u + i) * V_);
    } else {
#pragma unroll
      for (int k = 0; k < 3; ++k)
#pragma unroll
        for (int i = 0; i < 4; ++i)
          cvf[k][i] = *(const f32x4*)(cbf + (size_t)k * V_ * V_ + (u + i) * V_);
    }
  };
  // product + transposed swizzled write, all post-barrier (keeps regs low)
  auto productWriteA = [&]() {
    if constexpr (F16C) {
      half4v a16[4];
#pragma unroll
      for (int i = 0; i < 4; ++i) {
        a16[i][0] = (f16)pa[i][0]; a16[i][1] = (f16)pa[i][1];
        a16[i][2] = (f16)pa[i][2]; a16[i][3] = (f16)pa[i][3];
      }
#pragma unroll
      for (int k = 0; k < 3; ++k)
#pragma unroll
        for (int j = 0; j < 4; ++j) {
          int vr = vsub + j;
          half4v h;
          h[0] = cv16[k][0][j] * a16[0][j]; h[1] = cv16[k][1][j] * a16[1][j];
          h[2] = cv16[k][2][j] * a16[2][j]; h[3] = cv16[k][3][j] * a16[3][j];
          *(half4v*)(Ab + k * 8192 + vr * 128 + ((usub * 2) ^ ((vr & 7) << 4))) = h;
        }
    } else {
#pragma unroll
      for (int k = 0; k < 3; ++k)
#pragma unroll
        for (int j = 0; j < 4; ++j) {
          int vr = vsub + j;
          half4v h;
          h[0] = (f16)(cvf[k][0][j] * pa[0][j]); h[1] = (f16)(cvf[k][1][j] * pa[1][j]);
          h[2] = (f16)(cvf[k][2][j] * pa[2][j]); h[3] = (f16)(cvf[k][3][j] * pa[3][j]);
          *(half4v*)(Ab + k * 8192 + vr * 128 + ((usub * 2) ^ ((vr & 7) << 4))) = h;
        }
    }
  };

  // ---- prologue ----
  issueA(ubase);
  stageB(ubase, Bbuf0);
  productWriteA();
  __syncthreads();

  for (int t = 0; t < NSTEP; ++t) {
    char* Bc = (t & 1) ? Bbuf1 : Bbuf0;
    char* Bn = (t & 1) ? Bbuf0 : Bbuf1;
    const bool pref = (t + 1) < NSTEP;
    const size_t unext = ubase + (size_t)(t + 1) * 64;

    if (pref) {
      issueA(unext);          // att/cheb loads fly across the compute phase
      stageB(unext, Bn);      // glds fly across the compute phase
    }

    COMPUTE_KS(0, Bc)
    COMPUTE_KS(1, Bc)
    COMPUTE_KS(2, Bc)
    COMPUTE_KS(3, Bc)

    __syncthreads();          // vmcnt drain: loads had full compute in flight
    if (pref) productWriteA();
    __syncthreads();          // lgkm-only drain (no outstanding vmem)
  }

  // ---- epilogue: scatter acc -> rhs[b][t][v][uh*48 + k*16 + f] (f16) ----
#pragma unroll
  for (int nf = 0; nf < 3; ++nf) {
    int n = wn * 96 + nf * 32 + (lane & 31);
    int tt = n >> 4, fi = n & 15;
#pragma unroll
    for (int k = 0; k < 3; ++k) {
#pragma unroll
      for (int r = 0; r < 16; ++r) {
        int v = vbase + wm * 32 + (r & 3) + 8 * (r >> 2) + 4 * (lane >> 5);
        rhs[((size_t)(b * T_ + tt) * V_ + v) * (48 * UH) + uh * 48 + k * 16 + fi] =
            (f16)acc[k][nf][r];
      }
    }
  }
}
#undef COMPUTE_KS

// ---------------------------------------------------------------------------
// Kernel 3: out[row, c] = relu( sum_{s} rhs[row][s*16+..] * theta[(s%3)*16+..][c] )
// ---------------------------------------------------------------------------
template<int UH>
__global__ __launch_bounds__(256) void epi(const f16* __restrict__ rhs,
                                           const float* __restrict__ theta,
                                           float* __restrict__ out) {
  int wave = threadIdx.x >> 6, lane = threadIdx.x & 63;
  int row0 = blockIdx.x * 128 + wave * 32;
  int cl = lane & 31, kh = (lane >> 5) * 8;

  half8v bf[2][3];
#pragma unroll
  for (int nf = 0; nf < 2; ++nf)
#pragma unroll
    for (int ks = 0; ks < 3; ++ks) {
      half8v hb;
#pragma unroll
      for (int j = 0; j < 8; ++j)
        hb[j] = (f16)theta[(size_t)(ks * 16 + kh + j) * C_ + nf * 32 + cl];
      bf[nf][ks] = hb;
    }

  f32x16 acc0 = 0, acc1 = 0;
#pragma unroll
  for (int s = 0; s < 3 * UH; ++s) {
    half8v a = *(const half8v*)(rhs + (size_t)(row0 + cl) * (48 * UH) + s * 16 + kh);
    acc0 = __builtin_amdgcn_mfma_f32_32x32x16_f16(a, bf[0][s % 3], acc0, 0, 0, 0);
    acc1 = __builtin_amdgcn_mfma_f32_32x32x16_f16(a, bf[1][s % 3], acc1, 0, 0, 0);
  }
#pragma unroll
  for (int r = 0; r < 16; ++r) {
    int row = row0 + (r & 3) + 8 * (r >> 2) + 4 * (lane >> 5);
    out[(size_t)row * C_ + cl]      = fmaxf(acc0[r], 0.f);
    out[(size_t)row * C_ + 32 + cl] = fmaxf(acc1[r], 0.f);
  }
}

// ---------------------------------------------------------------------------
extern "C" void kernel_launch(void* const* d_in, const int* in_sizes, int n_in,
                              void* d_out, int out_size, void* d_ws, size_t ws_size,
                              hipStream_t stream) {
  const float* x     = (const float*)d_in[0];   // (8,12,2048,16)
  const float* Att   = (const float*)d_in[1];   // (8,2048,2048)
  const float* cheb  = (const float*)d_in[2];   // (3,2048,2048)
  const float* theta = (const float*)d_in[3];   // (3,16,64)
  float* out = (float*)d_out;                   // (8,12,2048,64) fp32

  const size_t xtB   = (size_t)B_ * N_ * V_ * sizeof(f16);        // 6.29 MB
  const size_t rhs2B = (size_t)B_ * T_ * V_ * 96 * sizeof(f16);   // 37.7 MB
  const size_t rhs1B = rhs2B / 2;                                 // 18.9 MB
  const size_t chB   = (size_t)K_ * V_ * V_ * sizeof(f16);        // 25.2 MB

  f16* XT = (f16*)d_ws;
  prep_xt<<<B_ * T_ * 4, 256, 0, stream>>>(x, XT);

  if (ws_size >= xtB + rhs2B + chB) {
    f16* rhs = (f16*)((char*)d_ws + xtB);
    f16* c16 = (f16*)((char*)d_ws + xtB + rhs2B);
    prep_cheb<<<(K_ * V_ * V_) / 1024, 256, 0, stream>>>(cheb, c16);
    gemm_fused<2, true><<<B_ * 32 * 2, 256, 0, stream>>>(Att, c16, XT, rhs);
    epi<2><<<(B_ * T_ * V_) / 128, 256, 0, stream>>>(rhs, theta, out);
  } else if (ws_size >= xtB + rhs1B + chB) {
    f16* rhs = (f16*)((char*)d_ws + xtB);
    f16* c16 = (f16*)((char*)d_ws + xtB + rhs1B);
    prep_cheb<<<(K_ * V_ * V_) / 1024, 256, 0, stream>>>(cheb, c16);
    gemm_fused<1, true><<<B_ * 32, 256, 0, stream>>>(Att, c16, XT, rhs);
    epi<1><<<(B_ * T_ * V_) / 128, 256, 0, stream>>>(rhs, theta, out);
  } else {
    f16* rhs = (f16*)((char*)d_ws + xtB);
    gemm_fused<1, false><<<B_ * 32, 256, 0, stream>>>(Att, cheb, XT, rhs);
    epi<1><<<(B_ * T_ * V_) / 128, 256, 0, stream>>>(rhs, theta, out);
  }
}

// Round 6
// 112.609 us; speedup vs baseline: 1.0622x; 1.0622x over previous
//
#include <hip/hip_runtime.h>
#include <hip/hip_bf16.h>
#include <stdint.h>

// cheb_conv_with_Att_static: out[b,t,v,c] = relu( sum_{k,f} theta[k,f,c] *
//     sum_u cheb[k,u,v]*Att[b,u,v]*x[b,t,u,f] )
// B=8 T=12 V=2048 F=16 K=3 C=64
#define B_  8
#define T_  12
#define V_  2048
#define F_  16
#define K_  3
#define C_  64
#define N_  192   // T*F

typedef _Float16 f16;
typedef _Float16 half4v __attribute__((ext_vector_type(4)));
typedef _Float16 half8v __attribute__((ext_vector_type(8)));
typedef float    f32x4  __attribute__((ext_vector_type(4)));
typedef float    f32x16 __attribute__((ext_vector_type(16)));
typedef unsigned int u32;

// ---------------------------------------------------------------------------
// Kernel 1a: XT[b][n=t*16+f][u] = (f16) x[b][t][u][f]   (u becomes contiguous)
// ---------------------------------------------------------------------------
__global__ __launch_bounds__(256) void prep_xt(const float* __restrict__ x,
                                               f16* __restrict__ XT) {
  int bid = blockIdx.x;
  int bt = bid >> 2, uc = bid & 3;
  int b = bt / T_, t = bt % T_;
  __shared__ float tile[64][17];
  int r  = threadIdx.x >> 2, fq = threadIdx.x & 3;   // load mapping
  int f  = threadIdx.x >> 4, uq = threadIdx.x & 15;  // store mapping
  for (int u0 = uc * 512; u0 < uc * 512 + 512; u0 += 64) {
    f32x4 v = *(const f32x4*)(x + ((size_t)(b * T_ + t) * V_ + u0 + r) * F_ + fq * 4);
    tile[r][fq * 4 + 0] = v[0];
    tile[r][fq * 4 + 1] = v[1];
    tile[r][fq * 4 + 2] = v[2];
    tile[r][fq * 4 + 3] = v[3];
    __syncthreads();
    half4v h;
    h[0] = (f16)tile[uq * 4 + 0][f];
    h[1] = (f16)tile[uq * 4 + 1][f];
    h[2] = (f16)tile[uq * 4 + 2][f];
    h[3] = (f16)tile[uq * 4 + 3][f];
    *(half4v*)(XT + (size_t)(b * N_ + t * F_ + f) * V_ + u0 + uq * 4) = h;
    __syncthreads();
  }
}

// ---------------------------------------------------------------------------
// Kernel 1b: chebT = f16 transpose of cheb in fragment-native blocked layout:
//   elem(k,v,u) at ((((k*64 + (v>>5))*256 + (u>>3))*32 + (v&31))*8 + (u&7))
// so an MFMA A-fragment (8 contiguous u at fixed v, 32 consecutive v across
// lanes) is ONE coalesced 16B/lane load.  3*32*32 = 3072 blocks.
// ---------------------------------------------------------------------------
__global__ __launch_bounds__(256) void prep_chebT(const float* __restrict__ c,
                                                  f16* __restrict__ cT) {
  int bid = blockIdx.x;
  int vt = bid & 31, ut = (bid >> 5) & 31, k = bid >> 10;
  int u0 = ut * 64, v0 = vt * 64;
  __shared__ float tile[64][68];
  int tid = threadIdx.x;
  int lr = tid >> 4, lc = (tid & 15) * 4;
  const float* src = c + ((size_t)k * V_ + u0) * V_ + v0;
#pragma unroll
  for (int i = 0; i < 4; ++i) {
    f32x4 v = *(const f32x4*)(src + (size_t)(lr + 16 * i) * V_ + lc);
    tile[lr + 16 * i][lc + 0] = v[0];
    tile[lr + 16 * i][lc + 1] = v[1];
    tile[lr + 16 * i][lc + 2] = v[2];
    tile[lr + 16 * i][lc + 3] = v[3];
  }
  __syncthreads();
  int vl = tid & 63, uc0 = tid >> 6;
#pragma unroll
  for (int i = 0; i < 2; ++i) {
    int uc = uc0 + 4 * i;
    half8v h;
#pragma unroll
    for (int j = 0; j < 8; ++j) h[j] = (f16)tile[uc * 8 + j][vl];
    int vb = (v0 + vl) >> 5;
    int vi = vl & 31;
    size_t ut_idx = (size_t)(u0 >> 3) + uc;
    size_t off = ((((size_t)k * 64 + vb) * 256 + ut_idx) * 32 + vi) * 8;
    *(half8v*)(cT + off) = h;
  }
}

// ---------------------------------------------------------------------------
// Kernel 2 (round-6): per (b,vt,uh), all 3 k:
//   rhs[b][t][v][uh*48+k*16+f] = sum_u (cheb[k,u,v]*Att[b,u,v]) * XT[b,n,u]
// BM=64 BN=192 BK=64, 4 waves (2x2), wave tile 32x96, 32x32x16 f16 MFMA.
// A-path split: cheb frags load DIRECTLY from blocked chebT (L2-hot via XCD
// swizzle bid%8==vt%8); LDS A holds att only (8KB, dbuf).  a = cheb_frag *
// att_frag in regs (v_pk_mul_f16).  B (XT) via glds, dbuf.  ONE barrier/step.
// A swizzle key ((vr+(vr>>3))&7)<<4: bank-optimal on b64 writes AND b128 reads.
// Regs: 144 acc + ~80 -> 2 waves/SIMD; LDS 64KB -> 2 blocks/CU.
// ---------------------------------------------------------------------------
#define MFMA_H(a, b, c) __builtin_amdgcn_mfma_f32_32x32x16_f16(a, b, c, 0, 0, 0)

#define KS_GROUP(ks, AC, BC)                                                   \
  {                                                                            \
    const int kb = (ks) * 32 + hi * 16;                                        \
    half8v af = *(const half8v*)((AC) + vrow * 128 + (kb ^ skey));             \
    half8v b0 = *(const half8v*)((BC) + nrow0 * 128 + (kb ^ bk0));             \
    half8v b1 = *(const half8v*)((BC) + nrow1 * 128 + (kb ^ bk1));             \
    half8v b2 = *(const half8v*)((BC) + nrow2 * 128 + (kb ^ bk2));             \
    const size_t co = (size_t)(t * 8 + (ks) * 2 + hi) * 256;                   \
    half8v c0 = *(const half8v*)(chb0 + co);                                   \
    half8v c1 = *(const half8v*)(chb1 + co);                                   \
    half8v c2 = *(const half8v*)(chb2 + co);                                   \
    half8v a0 = c0 * af, a1 = c1 * af, a2 = c2 * af;                           \
    __builtin_amdgcn_s_setprio(1);                                             \
    acc[0][0] = MFMA_H(a0, b0, acc[0][0]);                                     \
    acc[0][1] = MFMA_H(a0, b1, acc[0][1]);                                     \
    acc[0][2] = MFMA_H(a0, b2, acc[0][2]);                                     \
    acc[1][0] = MFMA_H(a1, b0, acc[1][0]);                                     \
    acc[1][1] = MFMA_H(a1, b1, acc[1][1]);                                     \
    acc[1][2] = MFMA_H(a1, b2, acc[1][2]);                                     \
    acc[2][0] = MFMA_H(a2, b0, acc[2][0]);                                     \
    acc[2][1] = MFMA_H(a2, b1, acc[2][1]);                                     \
    acc[2][2] = MFMA_H(a2, b2, acc[2][2]);                                     \
    __builtin_amdgcn_s_setprio(0);                                             \
  }

template<int UH>
__global__ __launch_bounds__(256, 2) void gemm2(const float* __restrict__ Att,
                                                const f16* __restrict__ chebT,
                                                const f16* __restrict__ XT,
                                                f16* __restrict__ rhs) {
  constexpr int NSTEP = (V_ / UH) / 64;   // 16 (UH=2) / 32 (UH=1)
  const int bid = blockIdx.x;
  const int vt = bid & 31;                // bid%8 == vt%8 -> XCD-pinned cheb slice
  const int rr = bid >> 5;
  const int b  = rr / UH;
  const int uh = rr % UH;
  const int vbase = vt * 64;
  const size_t ubase = (size_t)uh * (V_ / UH);

  __shared__ char smem[65536];            // B0 24K | B1 24K | A0 8K | A1 8K
  char* Bb0 = smem;
  char* Bb1 = smem + 24576;
  char* Ab0 = smem + 49152;
  char* Ab1 = smem + 57344;

  const int tid = threadIdx.x;
  const int wave = tid >> 6, lane = tid & 63;
  const int wm = wave >> 1, wn = wave & 1;
  const int hi = lane >> 5, l31 = lane & 31;
  const int vrow = wm * 32 + l31;
  const int vsub = (tid & 15) * 4, usub = (tid >> 4) * 4;

  const int skey = ((vrow + (vrow >> 3)) & 7) << 4;
  const int nrow0 = wn * 96 + l31;
  const int nrow1 = nrow0 + 32;
  const int nrow2 = nrow0 + 64;
  const int bk0 = (nrow0 & 7) << 4, bk1 = (nrow1 & 7) << 4, bk2 = (nrow2 & 7) << 4;

  // cheb lane base: frag (k,ks,t) = chbK + (t*8 + ks*2 + hi)*256  (elems)
  const int vb = vt * 2 + wm;
  const f16* chb0 = chebT + (((size_t)vb * 256 + (ubase >> 3)) * 32 + l31) * 8;
  const f16* chb1 = chb0 + (size_t)V_ * V_;
  const f16* chb2 = chb1 + (size_t)V_ * V_;

  const float* attb = Att + (size_t)b * V_ * V_ + (ubase + usub) * V_ + vbase + vsub;
  const f16*   xtb  = XT + (size_t)b * N_ * V_ + ubase;

  f32x16 acc[3][3];
#pragma unroll
  for (int k = 0; k < 3; ++k)
#pragma unroll
    for (int nf = 0; nf < 3; ++nf) acc[k][nf] = 0;

  f32x4 pa[4];
  const int gl_c = lane & 7;              // dest chunk; src chunk = gl_c^(n&7)

  auto stageB = [&](int t, char* Bb) {
#pragma unroll
    for (int e = 0; e < 6; ++e) {
      int slot = wave * 6 + e;
      int n = slot * 8 + (lane >> 3);
      int cc = gl_c ^ (n & 7);
      const f16* src = xtb + (size_t)n * V_ + t * 64 + cc * 8;
      __builtin_amdgcn_global_load_lds((const __attribute__((address_space(1))) u32*)src,
                                       (__attribute__((address_space(3))) u32*)(Bb + slot * 1024),
                                       16, 0, 0);
    }
  };
  auto issueAtt = [&](int t) {
#pragma unroll
    for (int i = 0; i < 4; ++i)
      pa[i] = *(const f32x4*)(attb + (size_t)(t * 64 + i) * V_);
  };
  auto writeAtt = [&](char* Aw) {
#pragma unroll
    for (int j = 0; j < 4; ++j) {
      int vr = vsub + j;
      half4v h;
      h[0] = (f16)pa[0][j]; h[1] = (f16)pa[1][j];
      h[2] = (f16)pa[2][j]; h[3] = (f16)pa[3][j];
      *(half4v*)(Aw + vr * 128 + ((usub * 2) ^ (((vr + (vr >> 3)) & 7) << 4))) = h;
    }
  };

  // ---- prologue: stage step 0 ----
  issueAtt(0);
  stageB(0, Bb0);
  writeAtt(Ab0);
  __syncthreads();

#pragma unroll 1
  for (int t0 = 0; t0 < NSTEP; t0 += 2) {
    {
      const int t = t0;
      issueAtt(t + 1);
      stageB(t + 1, Bb1);
      KS_GROUP(0, Ab0, Bb0)
      KS_GROUP(1, Ab0, Bb0)
      KS_GROUP(2, Ab0, Bb0)
      KS_GROUP(3, Ab0, Bb0)
      writeAtt(Ab1);
      __syncthreads();
    }
    {
      const int t = t0 + 1;
      const bool p2 = (t + 1) < NSTEP;
      if (p2) { issueAtt(t + 1); stageB(t + 1, Bb0); }
      KS_GROUP(0, Ab1, Bb1)
      KS_GROUP(1, Ab1, Bb1)
      KS_GROUP(2, Ab1, Bb1)
      KS_GROUP(3, Ab1, Bb1)
      if (p2) writeAtt(Ab0);
      __syncthreads();
    }
  }

  // ---- epilogue: scatter acc -> rhs[b][t][v][uh*48 + k*16 + f] (f16) ----
#pragma unroll
  for (int nf = 0; nf < 3; ++nf) {
    int n = wn * 96 + nf * 32 + l31;
    int tt = n >> 4, fi = n & 15;
#pragma unroll
    for (int k = 0; k < 3; ++k) {
#pragma unroll
      for (int r = 0; r < 16; ++r) {
        int v = vbase + wm * 32 + (r & 3) + 8 * (r >> 2) + 4 * hi;
        rhs[((size_t)(b * T_ + tt) * V_ + v) * (48 * UH) + uh * 48 + k * 16 + fi] =
            (f16)acc[k][nf][r];
      }
    }
  }
}

// ---------------------------------------------------------------------------
// Kernel 3: out[row, c] = relu( sum_{s} rhs[row][s*16+..] * theta[(s%3)*16+..][c] )
// ---------------------------------------------------------------------------
template<int UH>
__global__ __launch_bounds__(256) void epi(const f16* __restrict__ rhs,
                                           const float* __restrict__ theta,
                                           float* __restrict__ out) {
  int wave = threadIdx.x >> 6, lane = threadIdx.x & 63;
  int row0 = blockIdx.x * 128 + wave * 32;
  int cl = lane & 31, kh = (lane >> 5) * 8;

  half8v bf[2][3];
#pragma unroll
  for (int nf = 0; nf < 2; ++nf)
#pragma unroll
    for (int ks = 0; ks < 3; ++ks) {
      half8v hb;
#pragma unroll
      for (int j = 0; j < 8; ++j)
        hb[j] = (f16)theta[(size_t)(ks * 16 + kh + j) * C_ + nf * 32 + cl];
      bf[nf][ks] = hb;
    }

  f32x16 acc0 = 0, acc1 = 0;
#pragma unroll
  for (int s = 0; s < 3 * UH; ++s) {
    half8v a = *(const half8v*)(rhs + (size_t)(row0 + cl) * (48 * UH) + s * 16 + kh);
    acc0 = __builtin_amdgcn_mfma_f32_32x32x16_f16(a, bf[0][s % 3], acc0, 0, 0, 0);
    acc1 = __builtin_amdgcn_mfma_f32_32x32x16_f16(a, bf[1][s % 3], acc1, 0, 0, 0);
  }
#pragma unroll
  for (int r = 0; r < 16; ++r) {
    int row = row0 + (r & 3) + 8 * (r >> 2) + 4 * (lane >> 5);
    out[(size_t)row * C_ + cl]      = fmaxf(acc0[r], 0.f);
    out[(size_t)row * C_ + 32 + cl] = fmaxf(acc1[r], 0.f);
  }
}

// ---------------------------------------------------------------------------
extern "C" void kernel_launch(void* const* d_in, const int* in_sizes, int n_in,
                              void* d_out, int out_size, void* d_ws, size_t ws_size,
                              hipStream_t stream) {
  const float* x     = (const float*)d_in[0];   // (8,12,2048,16)
  const float* Att   = (const float*)d_in[1];   // (8,2048,2048)
  const float* cheb  = (const float*)d_in[2];   // (3,2048,2048)
  const float* theta = (const float*)d_in[3];   // (3,16,64)
  float* out = (float*)d_out;                   // (8,12,2048,64) fp32

  const size_t xtB   = (size_t)B_ * N_ * V_ * sizeof(f16);        // 6.29 MB
  const size_t rhs2B = (size_t)B_ * T_ * V_ * 96 * sizeof(f16);   // 37.7 MB
  const size_t rhs1B = rhs2B / 2;                                 // 18.9 MB
  const size_t chB   = (size_t)K_ * V_ * V_ * sizeof(f16);        // 25.2 MB

  f16* XT = (f16*)d_ws;
  prep_xt<<<B_ * T_ * 4, 256, 0, stream>>>(x, XT);

  if (ws_size >= xtB + rhs2B + chB) {
    f16* rhs = (f16*)((char*)d_ws + xtB);
    f16* cT  = (f16*)((char*)d_ws + xtB + rhs2B);
    prep_chebT<<<K_ * 32 * 32, 256, 0, stream>>>(cheb, cT);
    gemm2<2><<<B_ * 32 * 2, 256, 0, stream>>>(Att, cT, XT, rhs);
    epi<2><<<(B_ * T_ * V_) / 128, 256, 0, stream>>>(rhs, theta, out);
  } else {
    f16* rhs = (f16*)((char*)d_ws + xtB);
    f16* cT  = (f16*)((char*)d_ws + xtB + rhs1B);
    prep_chebT<<<K_ * 32 * 32, 256, 0, stream>>>(cheb, cT);
    gemm2<1><<<B_ * 32, 256, 0, stream>>>(Att, cT, XT, rhs);
    epi<1><<<(B_ * T_ * V_) / 128, 256, 0, stream>>>(rhs, theta, out);
  }
}